// Round 12
// baseline (502.894 us; speedup 1.0000x reference)
//
#include <hip/hip_runtime.h>
#include <math.h>

// ComponentPointPredictor: ragged autoregressive point prediction.
// Round 12: r11's verified shape, attacking the measured bottleneck (L2
// weight-stream latency; r11 proof: halving FMA work changed nothing,
// VALUBusy 42->25%). Changes:
//  (1) IT=8 (NBLK=512, 2 blocks/CU): hid_W amortized over 8 items, pred_W
//      loads shared across 2 items/wave -> per-item L2 traffic halved.
//  (2) Hand rotating prefetch: 2 groups (8 scalar loads) in flight on the
//      hid_W loop, 1 group on pred_W -- explicit SW pipelining (the rolled
//      loop holds only 4 loads in flight; ~200cy L2 latency exposed).
//  (3) 2 fp32 chains/item + in_W chain, combined in fp64 (r10/r11 class,
//      validated absmax 0.039 vs threshold 5.12).
// fp32 temp-50000 softmax -> soft-argmax -> floor chain op-for-op (r2).
// No unroll pragmas on weight loops (r7/r8); launch_bounds backstop (r10).

#define CTX     256
#define INIT    32
#define HID     256
#define WIN     63
#define MSTEPS  224            // CTX - INIT
#define OUTROW  (MSTEPS + CTX) // 480
#define IT      8
#define NT      256

__global__ void __launch_bounds__(NT, 4)
cpp_kernel(const float* __restrict__ x,
           const float* __restrict__ hid_W,
           const float* __restrict__ hid_b,
           const float* __restrict__ in_W,
           const float* __restrict__ in_b,
           const float* __restrict__ pred_W,
           const float* __restrict__ pred_b,
           float* __restrict__ out)
{
    __shared__ float s_x[IT][CTX];       // 8 KB fp32 x rows (broadcast reads)
    __shared__ float s_hid[IT][HID];     // 8 KB fp32 hidden carry
    __shared__ int   s_lastl[IT];
    __shared__ int   s_act[IT];

    const int tid  = threadIdx.x;
    const int lane = tid & 63;
    const int q    = tid >> 6;           // wave 0..3: owns items 2q, 2q+1
    const int j    = tid;                // hidden unit (NT == HID)
    const int item0 = blockIdx.x * IT;

    const double bias  = (double)hid_b[j] + (double)in_b[j];
    const float  pbias = (lane < WIN) ? pred_b[lane] : 0.0f;

    // ---- init: wave q inits items 2q, 2q+1 ----
    #pragma unroll
    for (int s = 0; s < 2; ++s) {
        const int it = 2 * q + s;
        const int item = item0 + it;
        float* orow = out + (size_t)item * OUTROW;
        for (int idx = lane; idx < OUTROW; idx += 64) orow[idx] = 0.0f;
        #pragma unroll
        for (int u = 0; u < 4; ++u)
            s_x[it][lane + 64 * u] = x[(size_t)item * CTX + lane + 64 * u];
        #pragma unroll
        for (int u = 0; u < 4; ++u) s_hid[it][lane + 64 * u] = 1.0f;
        if (lane == 0) { s_lastl[it] = INIT; s_act[it] = 1; }
    }

    float lastA = (float)INIT, lastB = (float)INIT;  // wave-local item state
    int   scA = 0, scB = 0;
    __syncthreads();

    for (int iter = 0; iter < MSTEPS; ++iter) {
        int lastl[IT], act[IT];
        #pragma unroll
        for (int it = 0; it < IT; ++it) { lastl[it] = s_lastl[it]; act[it] = s_act[it]; }
        {
            int any = 0;
            #pragma unroll
            for (int it = 0; it < IT; ++it) any |= act[it];
            if (!any) break;
        }

        // ---- Phase A: fp32 split-chain 288-dot for unit j, 8 items ----
        float ain[IT];
        #pragma unroll
        for (int it = 0; it < IT; ++it) ain[it] = 0.0f;
        {
            int sb[IT];
            #pragma unroll
            for (int it = 0; it < IT; ++it) {
                int l = lastl[it]; if (l > CTX) l = CTX;
                sb[it] = l - INIT;                    // in [0, 224]
            }
            #pragma unroll 1
            for (int m = 0; m < INIT; ++m) {
                const float wv = in_W[m * HID + j];
                #pragma unroll
                for (int it = 0; it < IT; ++it)
                    ain[it] = fmaf(s_x[it][sb[it] + m], wv, ain[it]);
            }
        }

        float c0[IT], c1[IT];
        #pragma unroll
        for (int it = 0; it < IT; ++it) { c0[it] = 0.0f; c1[it] = 0.0f; }

        // hid_W: two 4-wide groups rotating, 8 scalar loads in flight
        float a0 = hid_W[(size_t)0 * HID + j], a1 = hid_W[(size_t)1 * HID + j];
        float a2 = hid_W[(size_t)2 * HID + j], a3 = hid_W[(size_t)3 * HID + j];
        float b0 = hid_W[(size_t)4 * HID + j], b1 = hid_W[(size_t)5 * HID + j];
        float b2 = hid_W[(size_t)6 * HID + j], b3 = hid_W[(size_t)7 * HID + j];
        #pragma unroll 1
        for (int k = 0; k < HID; k += 8) {
            const int ka = (k + 8)  & (HID - 1);      // wrap: harmless dummy at tail
            const float na0 = hid_W[(size_t)(ka + 0) * HID + j];
            const float na1 = hid_W[(size_t)(ka + 1) * HID + j];
            const float na2 = hid_W[(size_t)(ka + 2) * HID + j];
            const float na3 = hid_W[(size_t)(ka + 3) * HID + j];
            #pragma unroll
            for (int it = 0; it < IT; ++it) {
                const float4 h = *(const float4*)&s_hid[it][k];
                c0[it] = fmaf(h.y, a1, fmaf(h.x, a0, c0[it]));
                c1[it] = fmaf(h.w, a3, fmaf(h.z, a2, c1[it]));
            }
            a0 = na0; a1 = na1; a2 = na2; a3 = na3;
            const int kb = (k + 12) & (HID - 1);
            const float nb0 = hid_W[(size_t)(kb + 0) * HID + j];
            const float nb1 = hid_W[(size_t)(kb + 1) * HID + j];
            const float nb2 = hid_W[(size_t)(kb + 2) * HID + j];
            const float nb3 = hid_W[(size_t)(kb + 3) * HID + j];
            #pragma unroll
            for (int it = 0; it < IT; ++it) {
                const float4 h = *(const float4*)&s_hid[it][k + 4];
                c0[it] = fmaf(h.y, b1, fmaf(h.x, b0, c0[it]));
                c1[it] = fmaf(h.w, b3, fmaf(h.z, b2, c1[it]));
            }
            b0 = nb0; b1 = nb1; b2 = nb2; b3 = nb3;
        }
        __syncthreads();   // (1) all old-s_hid reads done

        #pragma unroll
        for (int it = 0; it < IT; ++it) {
            if (act[it]) {
                const double tot = bias + (double)ain[it]
                                 + (double)c0[it] + (double)c1[it];
                s_hid[it][j] = tanhf((float)tot);
            }
        }
        __syncthreads();   // (2) new hidden visible

        // ---- Phase B: w[lane] for items 2q, 2q+1 (shared pred_W loads) ----
        const int itA = 2 * q, itB = 2 * q + 1;
        float tA = -INFINITY, tB = -INFINITY;
        if (lane < WIN && (act[itA] | act[itB])) {
            float pA0 = 0.0f, pA1 = 0.0f, pB0 = 0.0f, pB1 = 0.0f;
            float g0 = pred_W[0 * WIN + lane], g1 = pred_W[1 * WIN + lane];
            float g2 = pred_W[2 * WIN + lane], g3 = pred_W[3 * WIN + lane];
            #pragma unroll 1
            for (int k = 0; k < HID; k += 4) {
                const int kn = (k + 4) & (HID - 1);
                const float n0 = pred_W[(kn + 0) * WIN + lane];
                const float n1 = pred_W[(kn + 1) * WIN + lane];
                const float n2 = pred_W[(kn + 2) * WIN + lane];
                const float n3 = pred_W[(kn + 3) * WIN + lane];
                const float4 hA = *(const float4*)&s_hid[itA][k];
                const float4 hB = *(const float4*)&s_hid[itB][k];
                pA0 = fmaf(hA.y, g1, fmaf(hA.x, g0, pA0));
                pA1 = fmaf(hA.w, g3, fmaf(hA.z, g2, pA1));
                pB0 = fmaf(hB.y, g1, fmaf(hB.x, g0, pB0));
                pB1 = fmaf(hB.w, g3, fmaf(hB.z, g2, pB1));
                g0 = n0; g1 = n1; g2 = n2; g3 = n3;
            }
            tA = (float)((double)pbias + (double)pA0 + (double)pA1) * 50000.0f;
            tB = (float)((double)pbias + (double)pB0 + (double)pB1) * 50000.0f;
        }

        // ---- Phase C: fp32 softmax chain per item (mirrors ref) ----
        auto phaseC = [&](int it, float t, float& mylast, int& sc) {
            if (!act[it]) return;
            float mx = t;
            #pragma unroll
            for (int off = 32; off > 0; off >>= 1)
                mx = fmaxf(mx, __shfl_xor(mx, off));
            const float e = (lane < WIN) ? expf(t - mx) : 0.0f;
            float S = e;
            #pragma unroll
            for (int off = 32; off > 0; off >>= 1)
                S += __shfl_xor(S, off);
            const float p = e / S;
            float D = p * (float)lane;
            #pragma unroll
            for (int off = 32; off > 0; off >>= 1)
                D += __shfl_xor(D, off);
            float cur = fminf(D + 1.0f, 63.0f);
            float se = fminf(cur + mylast, 256.0f);
            const int sel = (int)se;

            float* orow = out + (size_t)(item0 + it) * OUTROW;
            if (lane < WIN) {
                const int pos = lastl[it] + lane;
                if (pos < sel) {
                    const float msk = 1.0f / (1.0f + expf((float)lane - cur));
                    orow[MSTEPS + pos] = msk * s_x[it][pos];
                }
            }
            const bool done = (se >= 256.0f);        // final step's pt is dropped
            if (lane == 0) {
                if (!done) { orow[sc] = se; s_lastl[it] = sel; }
                else       { s_act[it] = 0; }
            }
            sc++;
            mylast = se;
        };
        phaseC(itA, tA, lastA, scA);
        phaseC(itB, tB, lastB, scB);

        __syncthreads();   // (3) state updates visible for next Phase A
    }
}

extern "C" void kernel_launch(void* const* d_in, const int* in_sizes, int n_in,
                              void* d_out, int out_size, void* d_ws, size_t ws_size,
                              hipStream_t stream) {
    const float* x      = (const float*)d_in[0];
    const float* hid_W  = (const float*)d_in[1];
    const float* hid_b  = (const float*)d_in[2];
    const float* in_W   = (const float*)d_in[3];
    const float* in_b   = (const float*)d_in[4];
    const float* pred_W = (const float*)d_in[5];
    const float* pred_b = (const float*)d_in[6];
    float* out = (float*)d_out;

    const int B = in_sizes[0] / CTX;     // 4096
    const int nblocks = B / IT;          // 512
    cpp_kernel<<<nblocks, NT, 0, stream>>>(x, hid_W, hid_b, in_W, in_b,
                                           pred_W, pred_b, out);
}